// Round 10
// baseline (372.955 us; speedup 1.0000x reference)
//
#include <hip/hip_runtime.h>

// SpatialAttention B=4 HW=4096 C=256 NH=4 d=64 — f16 MFMA flash attention.
// R10 = R8 core (QTILE=256, 512-thr, NSPLIT=2, register-P PV) +
//  (a) combine fused into attn via last-finisher atomic per (qtile,bh)
//      (3 dispatches -> 2; each extra dispatch costs ~10-15us, combine ~9us),
//  (b) Q converted inline in attn prologue (Qhat tensor dropped from prepass),
//  (c) bit_cast fragment packing + dual fdot2 chains (VALU trim).
// R9 lesson: residency is register-bound (~96 unified VGPR -> 5 waves/SIMD,
// 2x8-wave blocks/CU); grid size beyond 512 adds nothing.

#define HW 4096
#define CCH 256
#define DH 64
#define NH 4
#define QTILE 256
#define KTILE 64
#define NSPLIT 2
#define NKT_SPLIT (HW / NSPLIT / KTILE)   // 32
#define LOG2E 1.44269504088896340736f

typedef __attribute__((ext_vector_type(8))) _Float16 half8;
typedef __attribute__((ext_vector_type(4))) _Float16 half4;
typedef __attribute__((ext_vector_type(2))) __fp16 pk16x2;   // cvt_pkrtz/fdot2 native type
typedef __attribute__((ext_vector_type(4))) float floatx4;

typedef struct { pk16x2 x, y; } pk16x4;          // -> half4 via bit_cast
typedef struct { pk16x2 x, y, z, w; } pk16x8;    // -> half8 via bit_cast

typedef __attribute__((address_space(1))) const unsigned int gbl_u32;
typedef __attribute__((address_space(3))) unsigned int lds_u32;

__device__ __forceinline__ void gload_lds16(const void* g, void* l) {
    __builtin_amdgcn_global_load_lds((gbl_u32*)g, (lds_u32*)l, 16, 0, 0);
}
__device__ __forceinline__ floatx4 mfma_k32(half8 a, half8 b, floatx4 c) {
    return __builtin_amdgcn_mfma_f32_16x16x32_f16(a, b, c, 0, 0, 0);
}
__device__ __forceinline__ floatx4 mfma_k16(half4 a, half4 b, floatx4 c) {
    return __builtin_amdgcn_mfma_f32_16x16x16f16(a, b, c, 0, 0, 0);
}

// ---------- fused prepass ----------
// blocks [0,4096): Khat elementwise f32->f16 (wk,bk folded)
// blocks [4096,5120): Vthat transpose into PV-fragment order + XOR swizzle
// block 5120: zero the 256 last-finisher counters
__global__ __launch_bounds__(256) void prepass_all(
    const float* __restrict__ k_in, const float* __restrict__ v_in,
    const float* __restrict__ wk, const float* __restrict__ bk,
    const float* __restrict__ wv, const float* __restrict__ bv,
    _Float16* __restrict__ Khat, _Float16* __restrict__ Vthat,
    int* __restrict__ cnt)
{
    if (blockIdx.x < 4096) {
        int idx = (blockIdx.x * 256 + threadIdx.x) * 4;
        int b = idx >> 20;
        int rem = idx & ((1 << 20) - 1);
        int row = rem >> 8;
        int c = rem & 255;
        int h = c >> 6;
        int ch = c & 63;
        floatx4 k4 = *(const floatx4*)(k_in + idx);
        floatx4 wk4 = *(const floatx4*)(wk + c);
        floatx4 bk4 = *(const floatx4*)(bk + c);
        pk16x2 lo = __builtin_amdgcn_cvt_pkrtz(k4.x * wk4.x + bk4.x,
                                               k4.y * wk4.y + bk4.y);
        pk16x2 hi = __builtin_amdgcn_cvt_pkrtz(k4.z * wk4.z + bk4.z,
                                               k4.w * wk4.w + bk4.w);
        half4 kh = __builtin_bit_cast(half4, (pk16x4){lo, hi});
        size_t o = ((size_t)(b * NH + h) * HW + row) * DH + ch;
        *(half4*)(Khat + o) = kh;
    } else if (blockIdx.x < 5120) {
        __shared__ _Float16 Lt[64 * 68];
        int bx = blockIdx.x - 4096;
        int t = threadIdx.x;
        int key0 = (bx & 63) * 64;
        int bh = bx >> 6;
        int b = bh >> 2, h = bh & 3;
        int c4 = (t & 15) * 4;
        floatx4 wv4 = *(const floatx4*)(wv + h * DH + c4);
        floatx4 bv4 = *(const floatx4*)(bv + h * DH + c4);
        #pragma unroll
        for (int p = 0; p < 4; ++p) {
            int key = p * 16 + (t >> 4);
            const float* vp = v_in + ((size_t)b * HW + key0 + key) * CCH + h * DH + c4;
            floatx4 v4 = *(const floatx4*)vp;
            pk16x2 lo = __builtin_amdgcn_cvt_pkrtz(v4.x * wv4.x + bv4.x,
                                                   v4.y * wv4.y + bv4.y);
            pk16x2 hi = __builtin_amdgcn_cvt_pkrtz(v4.z * wv4.z + bv4.z,
                                                   v4.w * wv4.w + bv4.w);
            *(half4*)(&Lt[key * 68 + c4]) = __builtin_bit_cast(half4, (pk16x4){lo, hi});
        }
        __syncthreads();
        // PV-fragment order + row XOR swizzle: stored group gpos of row d holds
        // data group g = gpos ^ (d&7); element j is key
        // key(g,j) = ((2g+(j>>2))&3)*16 + (g>>1)*4 + (j&3)
        #pragma unroll
        for (int p = 0; p < 2; ++p) {
            int d = p * 32 + (t >> 3);
            int gpos = t & 7;
            int g = gpos ^ (d & 7);
            half8 v8;
            #pragma unroll
            for (int j = 0; j < 8; ++j) {
                int key = (((g * 2 + (j >> 2)) & 3) << 4) + ((g >> 1) << 2) + (j & 3);
                v8[j] = Lt[key * 68 + d];
            }
            *(half8*)(Vthat + ((size_t)bh * DH + d) * HW + key0 + gpos * 8) = v8;
        }
    } else {
        cnt[threadIdx.x] = 0;   // 256 counters
    }
}

// ---------- attention (transposed, register-P, 2-way key-split, fused combine) ----------
__launch_bounds__(512, 4)
__global__ void attn_kernel(
    const float* __restrict__ q_in,
    const float* __restrict__ wq, const float* __restrict__ bq,
    const _Float16* __restrict__ Khat, const _Float16* __restrict__ Vthat,
    const float* __restrict__ wp, const float* __restrict__ bp,
    _Float16* __restrict__ Pacc, float* __restrict__ Pml,
    int* __restrict__ cnt, float* __restrict__ out)
{
    __shared__ alignas(16) char pool[32768];
    __shared__ int isLast;
    _Float16* Ksm0 = (_Float16*)(pool);
    _Float16* Ksm1 = (_Float16*)(pool + 8192);
    _Float16* Vsm0 = (_Float16*)(pool + 16384);
    _Float16* Vsm1 = (_Float16*)(pool + 24576);

    const int tid = threadIdx.x;
    const int wave = tid >> 6;
    const int lane = tid & 63;
    const int l15 = lane & 15;
    const int quad = lane >> 4;
    const int ksw = l15 & 7;

    const int qtile = blockIdx.x;
    const int bh = blockIdx.y;
    const int split = blockIdx.z;
    const int keybase = split * (HW / NSPLIT);
    const int b = bh >> 2, h = bh & 3, ch0 = h * DH;

    // ---- Q inline conversion -> B-frags (scale*log2e folded) ----
    const int q0 = qtile * QTILE + wave * 32;
    const float qsc = 0.125f * LOG2E;
    half8 qfrag[2][2];
    {
        const float* wqp = wq + ch0 + quad * 8;
        const float* bqp = bq + ch0 + quad * 8;
        floatx4 w0 = *(const floatx4*)(wqp);
        floatx4 w1 = *(const floatx4*)(wqp + 4);
        floatx4 w2 = *(const floatx4*)(wqp + 32);
        floatx4 w3 = *(const floatx4*)(wqp + 36);
        floatx4 b0 = *(const floatx4*)(bqp);
        floatx4 b1 = *(const floatx4*)(bqp + 4);
        floatx4 b2 = *(const floatx4*)(bqp + 32);
        floatx4 b3 = *(const floatx4*)(bqp + 36);
        #pragma unroll
        for (int g = 0; g < 2; ++g) {
            const float* qp = q_in + ((size_t)b * HW + q0 + g * 16 + l15) * CCH
                              + ch0 + quad * 8;
            floatx4 qa = *(const floatx4*)(qp);
            floatx4 qb = *(const floatx4*)(qp + 4);
            floatx4 qc = *(const floatx4*)(qp + 32);
            floatx4 qd = *(const floatx4*)(qp + 36);
            pk16x2 p0 = __builtin_amdgcn_cvt_pkrtz((qa.x*w0.x+b0.x)*qsc, (qa.y*w0.y+b0.y)*qsc);
            pk16x2 p1 = __builtin_amdgcn_cvt_pkrtz((qa.z*w0.z+b0.z)*qsc, (qa.w*w0.w+b0.w)*qsc);
            pk16x2 p2 = __builtin_amdgcn_cvt_pkrtz((qb.x*w1.x+b1.x)*qsc, (qb.y*w1.y+b1.y)*qsc);
            pk16x2 p3 = __builtin_amdgcn_cvt_pkrtz((qb.z*w1.z+b1.z)*qsc, (qb.w*w1.w+b1.w)*qsc);
            qfrag[g][0] = __builtin_bit_cast(half8, (pk16x8){p0, p1, p2, p3});
            p0 = __builtin_amdgcn_cvt_pkrtz((qc.x*w2.x+b2.x)*qsc, (qc.y*w2.y+b2.y)*qsc);
            p1 = __builtin_amdgcn_cvt_pkrtz((qc.z*w2.z+b2.z)*qsc, (qc.w*w2.w+b2.w)*qsc);
            p2 = __builtin_amdgcn_cvt_pkrtz((qd.x*w3.x+b3.x)*qsc, (qd.y*w3.y+b3.y)*qsc);
            p3 = __builtin_amdgcn_cvt_pkrtz((qd.z*w3.z+b3.z)*qsc, (qd.w*w3.w+b3.w)*qsc);
            qfrag[g][1] = __builtin_bit_cast(half8, (pk16x8){p0, p1, p2, p3});
        }
    }

    const int srow = wave * 8 + (lane >> 3);
    const int sw = (lane & 7) ^ (lane >> 3);
    const _Float16* kgp = Khat + ((size_t)bh * HW + keybase + srow) * DH + sw * 8;
    const _Float16* vgp = Vthat + ((size_t)bh * DH + srow) * HW + keybase + (lane & 7) * 8;

    floatx4 acc[2][4];
    float m_i[2], l_i[2];
    #pragma unroll
    for (int g = 0; g < 2; ++g) {
        m_i[g] = -1e30f; l_i[g] = 0.0f;
        #pragma unroll
        for (int nt = 0; nt < 4; ++nt) { floatx4 z = {0.f,0.f,0.f,0.f}; acc[g][nt] = z; }
    }
    const pk16x2 ones = {(__fp16)1.0f, (__fp16)1.0f};

    #define STAGE(kt, KB, VB) do {                                             \
        gload_lds16(kgp + (size_t)(kt) * (KTILE * DH), (KB) + wave * 512);     \
        gload_lds16(vgp + (size_t)(kt) * KTILE, (VB) + wave * 512);            \
    } while (0)

    #define COMPUTE(KB, VB) do {                                               \
        floatx4 S[2][4];                                                       \
        _Pragma("unroll")                                                      \
        for (int kt = 0; kt < 4; ++kt) {                                       \
            const _Float16* kr = (KB) + (l15 + 16 * kt) * 64;                  \
            half8 kf0 = *(const half8*)(kr + ((quad ^ ksw) * 8));              \
            half8 kf1 = *(const half8*)(kr + (((4 + quad) ^ ksw) * 8));        \
            _Pragma("unroll")                                                  \
            for (int g = 0; g < 2; ++g) {                                      \
                floatx4 s = {0.f, 0.f, 0.f, 0.f};                              \
                s = mfma_k32(kf0, qfrag[g][0], s);                             \
                s = mfma_k32(kf1, qfrag[g][1], s);                             \
                S[g][kt] = s;                                                  \
            }                                                                  \
        }                                                                      \
        half4 pfrag[2][4];                                                     \
        _Pragma("unroll")                                                      \
        for (int g = 0; g < 2; ++g) {                                          \
            float mx = fmaxf(fmaxf(fmaxf(S[g][0][0], S[g][0][1]),              \
                                   fmaxf(S[g][0][2], S[g][0][3])),             \
                             fmaxf(fmaxf(S[g][1][0], S[g][1][1]),              \
                                   fmaxf(S[g][1][2], S[g][1][3])));            \
            float mx2 = fmaxf(fmaxf(fmaxf(S[g][2][0], S[g][2][1]),             \
                                    fmaxf(S[g][2][2], S[g][2][3])),            \
                              fmaxf(fmaxf(S[g][3][0], S[g][3][1]),             \
                                    fmaxf(S[g][3][2], S[g][3][3])));           \
            mx = fmaxf(mx, mx2);                                               \
            mx = fmaxf(mx, __shfl_xor(mx, 16));                                \
            mx = fmaxf(mx, __shfl_xor(mx, 32));                                \
            if (__any(mx > m_i[g])) {                                          \
                float nm = fmaxf(m_i[g], mx);                                  \
                float alpha = __builtin_amdgcn_exp2f(m_i[g] - nm);             \
                l_i[g] *= alpha;                                               \
                _Pragma("unroll")                                              \
                for (int nt = 0; nt < 4; ++nt) acc[g][nt] *= alpha;            \
                m_i[g] = nm;                                                   \
            }                                                                  \
            float nm2 = m_i[g];                                                \
            float rsa = l_i[g], rsb = 0.0f;                                    \
            _Pragma("unroll")                                                  \
            for (int kt = 0; kt < 4; ++kt) {                                   \
                float p0 = __builtin_amdgcn_exp2f(S[g][kt][0] - nm2);          \
                float p1 = __builtin_amdgcn_exp2f(S[g][kt][1] - nm2);          \
                float p2 = __builtin_amdgcn_exp2f(S[g][kt][2] - nm2);          \
                float p3 = __builtin_amdgcn_exp2f(S[g][kt][3] - nm2);          \
                pk16x2 lo = __builtin_amdgcn_cvt_pkrtz(p0, p1);                \
                pk16x2 hi = __builtin_amdgcn_cvt_pkrtz(p2, p3);                \
                rsa = __builtin_amdgcn_fdot2(lo, ones, rsa, false);            \
                rsb = __builtin_amdgcn_fdot2(hi, ones, rsb, false);            \
                pfrag[g][kt] = __builtin_bit_cast(half4, (pk16x4){lo, hi});    \
            }                                                                  \
            l_i[g] = rsa + rsb;                                                \
        }                                                                      \
        _Pragma("unroll")                                                      \
        for (int c = 0; c < 2; ++c) {                                          \
            _Pragma("unroll")                                                  \
            for (int nt = 0; nt < 4; ++nt) {                                   \
                const _Float16* vr = (VB) + (l15 + 16 * nt) * 64               \
                    + (((quad * 2 + c) ^ ksw) * 8);                            \
                half8 vf = *(const half8*)vr;                                  \
                half4 va = __builtin_shufflevector(vf, vf, 0, 1, 2, 3);        \
                half4 vb = __builtin_shufflevector(vf, vf, 4, 5, 6, 7);        \
                acc[0][nt] = mfma_k16(va, pfrag[0][2 * c], acc[0][nt]);        \
                acc[1][nt] = mfma_k16(va, pfrag[1][2 * c], acc[1][nt]);        \
                acc[0][nt] = mfma_k16(vb, pfrag[0][2 * c + 1], acc[0][nt]);    \
                acc[1][nt] = mfma_k16(vb, pfrag[1][2 * c + 1], acc[1][nt]);    \
            }                                                                  \
        }                                                                      \
    } while (0)

    STAGE(0, Ksm0, Vsm0);
    for (int kt = 0; kt < NKT_SPLIT; kt += 2) {
        __syncthreads();
        if (kt + 1 < NKT_SPLIT) STAGE(kt + 1, Ksm1, Vsm1);
        COMPUTE(Ksm0, Vsm0);
        __syncthreads();
        if (kt + 2 < NKT_SPLIT) STAGE(kt + 2, Ksm0, Vsm0);
        COMPUTE(Ksm1, Vsm1);
    }

    // ---- partial epilogue: finish l, store normalized f16 O + (m,l) ----
    const int sb = (split << 4) | bh;
    #pragma unroll
    for (int g = 0; g < 2; ++g) {
        float lf = l_i[g];
        lf += __shfl_xor(lf, 16);
        lf += __shfl_xor(lf, 32);
        float inv_l = 1.0f / lf;
        int myq = q0 + g * 16 + l15;
        size_t pb = ((size_t)sb * HW + myq) * DH;
        #pragma unroll
        for (int nt = 0; nt < 4; ++nt) {
            pk16x2 lo = __builtin_amdgcn_cvt_pkrtz(acc[g][nt][0] * inv_l,
                                                   acc[g][nt][1] * inv_l);
            pk16x2 hi = __builtin_amdgcn_cvt_pkrtz(acc[g][nt][2] * inv_l,
                                                   acc[g][nt][3] * inv_l);
            *(half4*)(Pacc + pb + nt * 16 + quad * 4) =
                __builtin_bit_cast(half4, (pk16x4){lo, hi});
        }
        if (quad == 0) {
            float2 ml; ml.x = m_i[g]; ml.y = lf;
            *(float2*)(Pml + ((size_t)sb * HW + myq) * 2) = ml;
        }
    }

    // ---- last-finisher combine for this (qtile,bh) ----
    __threadfence();          // release our partial stores (agent scope)
    __syncthreads();          // all waves' stores+fences done
    if (tid == 0) {
        int old = atomicAdd(&cnt[qtile * 16 + bh], 1);
        isLast = (old == NSPLIT - 1);
    }
    __syncthreads();
    if (isLast) {
        __threadfence();      // acquire: see the other split's stores
        // 512 threads x 8 iters cover 256 q x 64 ch (half4 granularity)
        #pragma unroll
        for (int i = 0; i < 8; ++i) {
            int e = tid + i * 512;           // 0..4095
            int q = qtile * QTILE + (e >> 4);
            int c4 = (e & 15) * 4;
            size_t r0 = (size_t)bh * HW + q;             // split 0
            size_t r1 = (size_t)(16 + bh) * HW + q;      // split 1
            float2 ml0 = *(const float2*)(Pml + r0 * 2);
            float2 ml1 = *(const float2*)(Pml + r1 * 2);
            float m = fmaxf(ml0.x, ml1.x);
            float w0 = ml0.y * __builtin_amdgcn_exp2f(ml0.x - m);
            float w1 = ml1.y * __builtin_amdgcn_exp2f(ml1.x - m);
            float inv = 1.0f / (w0 + w1);
            w0 *= inv; w1 *= inv;
            half4 a0 = *(const half4*)(Pacc + r0 * DH + c4);
            half4 a1 = *(const half4*)(Pacc + r1 * DH + c4);
            floatx4 wp4 = *(const floatx4*)(wp + ch0 + c4);
            floatx4 bp4 = *(const floatx4*)(bp + ch0 + c4);
            floatx4 o;
            #pragma unroll
            for (int j = 0; j < 4; ++j)
                o[j] = ((float)a0[j] * w0 + (float)a1[j] * w1) * wp4[j] + bp4[j];
            *(floatx4*)(out + ((size_t)b * HW + q) * CCH + ch0 + c4) = o;
        }
    }
    #undef STAGE
    #undef COMPUTE
}

extern "C" void kernel_launch(void* const* d_in, const int* in_sizes, int n_in,
                              void* d_out, int out_size, void* d_ws, size_t ws_size,
                              hipStream_t stream) {
    const float* q_in = (const float*)d_in[0];
    const float* k_in = (const float*)d_in[1];
    const float* v_in = (const float*)d_in[2];
    const float* wq = (const float*)d_in[3];
    const float* bq = (const float*)d_in[4];
    const float* wk = (const float*)d_in[5];
    const float* bk = (const float*)d_in[6];
    const float* wv = (const float*)d_in[7];
    const float* bv = (const float*)d_in[8];
    const float* wp = (const float*)d_in[9];
    const float* bp = (const float*)d_in[10];
    float* out = (float*)d_out;

    const size_t tensor_halves = (size_t)4 * NH * HW * DH;   // 4 Mi halves = 8MB
    _Float16* Khat = (_Float16*)d_ws;                        //  8 MB
    _Float16* Vthat = Khat + tensor_halves;                  //  8 MB
    _Float16* Pacc = Vthat + tensor_halves;                  // 2 splits: 16.8 MB
    float* Pml = (float*)(Pacc + NSPLIT * tensor_halves);    //  1 MB
    int* cnt = (int*)(Pml + (size_t)NSPLIT * 16 * HW * 2);   //  1 KB

    prepass_all<<<dim3(5121), 256, 0, stream>>>(
        k_in, v_in, wk, bk, wv, bv, Khat, Vthat, cnt);
    attn_kernel<<<dim3(HW / QTILE, 4 * NH, NSPLIT), 512, 0, stream>>>(
        q_in, wq, bq, Khat, Vthat, wp, bp, Pacc, Pml, cnt, out);
}